// Round 14
// baseline (297.598 us; speedup 1.0000x reference)
//
#include <hip/hip_runtime.h>

// MultiHeadAttention3D: S=1024, B=8, E=1024, H=16, D=64.
// Pipeline: detect mask dtype -> cvt(f32->bf16) -> merged QKV proj GEMM (128x128,
//           BK=32, counted-vmcnt dbuf, 4 blocks/CU) -> V transpose -> fused flash
//           attention (swapped-QK, exp2-domain softmax) -> Wo GEMM (f32 out).

typedef __attribute__((ext_vector_type(8))) short bf16x8;       // MFMA A/B frag (8 bf16)
typedef __attribute__((ext_vector_type(8))) unsigned short u16x8;
typedef __attribute__((ext_vector_type(4))) float f32x4;
typedef __attribute__((ext_vector_type(4))) int i32x4;

#define LOG2E 1.44269504088896340736f

__device__ __forceinline__ unsigned short bfbits(float f) {    // f32 -> bf16 (RTNE)
  unsigned u = __builtin_bit_cast(unsigned, f);
  u += 0x7fffu + ((u >> 16) & 1u);
  return (unsigned short)(u >> 16);
}
__device__ __forceinline__ unsigned pk2(float a, float b) {
  return (unsigned)bfbits(a) | ((unsigned)bfbits(b) << 16);
}
__device__ __forceinline__ void async16(const void* src, void* dst_lds) {
  __builtin_amdgcn_global_load_lds(
      (const __attribute__((address_space(1))) unsigned int*)src,
      (__attribute__((address_space(3))) unsigned int*)dst_lds, 16, 0, 0);
}

// ---------------- mask dtype detection ----------------
__global__ void detect_mask(const unsigned* __restrict__ m, int* __restrict__ flag)
{
  unsigned ok = 1u;
#pragma unroll 8
  for (int i = 0; i < 64; ++i) {
    unsigned w = m[(threadIdx.x << 6) + i];
    ok &= (w <= 1u) ? 1u : 0u;
  }
  unsigned long long vote = __ballot(ok != 0u);
  if (threadIdx.x == 0) *flag = (vote == ~0ull) ? 1 : 0;
}

// ---------------- convert q,k,v,W* to bf16 ----------------
__global__ __launch_bounds__(256) void cvt_kernel(
    const float* __restrict__ q, const float* __restrict__ k, const float* __restrict__ v,
    const float* __restrict__ wq, const float* __restrict__ wk,
    const float* __restrict__ wv, const float* __restrict__ wo,
    unsigned short* __restrict__ Xin, unsigned short* __restrict__ Wbf)
{
  const unsigned u = blockIdx.x * 256u + threadIdx.x;   // 3670016 units of 8 elems
  const float* src;
  unsigned short* dst;
  if (u < 3145728u) {                      // q,k,v
    const unsigned z = u >> 20, r = u & 1048575u;
    src = (z == 0 ? q : z == 1 ? k : v) + (size_t)r * 8;
    dst = Xin + (size_t)z * 8388608u + (size_t)r * 8;
  } else {                                 // Wq,Wk,Wv,Wo
    const unsigned u2 = u - 3145728u, wz = u2 >> 17, r = u2 & 131071u;
    src = (wz == 0 ? wq : wz == 1 ? wk : wz == 2 ? wv : wo) + (size_t)r * 8;
    dst = Wbf + (size_t)wz * 1048576u + (size_t)r * 8;
  }
  f32x4 a = *(const f32x4*)src;
  f32x4 b = *(const f32x4*)(src + 4);
  uint4 o;
  o.x = pk2(a[0], a[1]); o.y = pk2(a[2], a[3]);
  o.z = pk2(b[0], b[1]); o.w = pk2(b[2], b[3]);
  *(uint4*)dst = o;
}

// ---------------- GEMM: 128x128 tile, BK=32, counted-vmcnt dbuf, 4 blocks/CU ----------------
// 4 waves (2x2, 64x64 each), LDS 32 KiB, launch_bounds(256,4) -> 16 waves/CU:
// 4 independent barrier groups per CU cover each other's stage stalls (m114).
// Schedule: vmcnt(4) [tile t landed, t+1 in flight] -> barrier -> ds_read+MFMA ->
// barrier -> stage(t+2). XOR chunk swizzle (rule #21, 4 chunks/row).
template<int OUTF32>
__global__ __launch_bounds__(256, 4) void gemm128(
    const unsigned short* __restrict__ A0,  // [M][K] bf16 (+ p*8388608)
    const unsigned short* __restrict__ B0,  // [N][K] bf16 (+ p*1048576)
    void* __restrict__ C0, float scale0, int M, int N, int K)
{
  const int tid = threadIdx.x;
  const int w = tid >> 6, lane = tid & 63, c = lane & 15, g = lane >> 4;
  const int wr = w >> 1, wc = w & 1;

  const int bid = blockIdx.x;
  const int p = bid >> 9, local = bid & 511;
  const unsigned short* A = A0 + (size_t)p * 8388608u;
  const unsigned short* B = B0 + (size_t)p * 1048576u;
  const float scale = (p == 0) ? scale0 : 1.0f;

  // XCD-chunked swizzle within the 512-block sub-grid
  const int swz = (local & 7) * 64 + (local >> 3);
  const int ntx = N >> 7;
  const int bx = swz % ntx, by = swz / ntx;
  const int rowA = by * 128, rowB = bx * 128;

  __shared__ unsigned short As[2][128 * 32];   // 2 x 8 KiB
  __shared__ unsigned short Bs[2][128 * 32];   // 2 x 8 KiB

  f32x4 acc[4][4];
#pragma unroll
  for (int i = 0; i < 4; ++i)
#pragma unroll
    for (int j = 0; j < 4; ++j) acc[i][j] = (f32x4){0.f, 0.f, 0.f, 0.f};

  const int wbase = (tid & ~63) * 16;          // wave-uniform LDS byte base (linear dest)

  // per tile: A rows 0..127 x 4 chunks (512 slots = 2 x 256 thr), same for B
#define STAGE(kt_, bb_) do { const int k0_ = (kt_) << 5;                          \
    _Pragma("unroll") for (int i_ = 0; i_ < 2; ++i_) {                            \
      const int slot_ = i_ * 256 + tid;                                           \
      const int row_ = slot_ >> 2;                                                \
      const int kc_ = (slot_ & 3) ^ (row_ & 3);                                   \
      async16(A + (size_t)(rowA + row_) * K + k0_ + kc_ * 8,                      \
              (char*)&As[bb_][0] + (i_ << 12) + wbase);                           \
      async16(B + (size_t)(rowB + row_) * K + k0_ + kc_ * 8,                      \
              (char*)&Bs[bb_][0] + (i_ << 12) + wbase);                           \
    } } while (0)

  // LDS[row][chunk j] holds global chunk j^(row&3); to read chunk g: j = g^(row&3)
#define RD(arr_, bb_, row_) \
    (*(const bf16x8*)&arr_[bb_][(row_) * 32 + (((g) ^ ((row_) & 3)) << 3)])

#define COMPUTE(bb_) do {                                                         \
    bf16x8 af_[4], bf_[4];                                                        \
    _Pragma("unroll") for (int x_ = 0; x_ < 4; ++x_) {                            \
      af_[x_] = RD(As, bb_, wr * 64 + x_ * 16 + c);                               \
      bf_[x_] = RD(Bs, bb_, wc * 64 + x_ * 16 + c);                               \
    }                                                                             \
    _Pragma("unroll") for (int mf_ = 0; mf_ < 4; ++mf_)                           \
      _Pragma("unroll") for (int nf_ = 0; nf_ < 4; ++nf_)                         \
        acc[mf_][nf_] = __builtin_amdgcn_mfma_f32_16x16x32_bf16(                  \
            af_[mf_], bf_[nf_], acc[mf_][nf_], 0, 0, 0); } while (0)

  STAGE(0, 0);
  STAGE(1, 1);

  const int nk = K >> 5;                       // 32
  for (int kt = 0; kt < nk - 1; ++kt) {
    asm volatile("s_waitcnt vmcnt(4)" ::: "memory");   // tile kt landed; kt+1 in flight
    __builtin_amdgcn_sched_barrier(0);
    __builtin_amdgcn_s_barrier();
    __builtin_amdgcn_sched_barrier(0);
    const int buf = kt & 1;
    COMPUTE(buf);
    __builtin_amdgcn_sched_barrier(0);
    __builtin_amdgcn_s_barrier();                      // all waves done reading buf
    __builtin_amdgcn_sched_barrier(0);
    if (kt < nk - 2) STAGE(kt + 2, buf);               // overwrite just-computed buf
  }
  asm volatile("s_waitcnt vmcnt(0)" ::: "memory");     // last tile landed
  __builtin_amdgcn_sched_barrier(0);
  __builtin_amdgcn_s_barrier();
  __builtin_amdgcn_sched_barrier(0);
  COMPUTE(1);

#undef STAGE
#undef RD
#undef COMPUTE

  const int r0 = rowA + wr * 64, c0 = rowB + wc * 64;
  if (OUTF32) {
    float* O = (float*)C0;
#pragma unroll
    for (int mf = 0; mf < 4; ++mf)
#pragma unroll
      for (int nf = 0; nf < 4; ++nf)
#pragma unroll
        for (int j = 0; j < 4; ++j)
          O[(size_t)(r0 + mf * 16 + g * 4 + j) * N + c0 + nf * 16 + c] = acc[mf][nf][j] * scale;
  } else {
    unsigned short* O = (unsigned short*)C0 + (size_t)p * 8388608u;
#pragma unroll
    for (int mf = 0; mf < 4; ++mf)
#pragma unroll
      for (int nf = 0; nf < 4; ++nf)
#pragma unroll
        for (int j = 0; j < 4; ++j)
          O[(size_t)(r0 + mf * 16 + g * 4 + j) * N + c0 + nf * 16 + c] = bfbits(acc[mf][nf][j] * scale);
  }
}

// ---------------- Vt[bh][d][s] = Vproj[(s*8+b)][h*64+d] ----------------
__global__ __launch_bounds__(256) void transpose_v(
    const unsigned short* __restrict__ Xp2, unsigned short* __restrict__ Vt)
{
  const int tid = threadIdx.x;
  const int bh = blockIdx.y, b = bh >> 4, h = bh & 15;
  const int s0 = blockIdx.x << 6;
  __shared__ unsigned short T[64 * 68];
#pragma unroll
  for (int p = 0; p < 2; ++p) {
    const int idx = (p << 8) + tid, sr = idx >> 3, ch2 = idx & 7;
    *(u16x8*)&T[sr * 68 + ch2 * 8] =
        *(const u16x8*)(Xp2 + ((size_t)((s0 + sr) * 8 + b) << 10) + (h << 6) + ch2 * 8);
  }
  __syncthreads();
#pragma unroll
  for (int p = 0; p < 2; ++p) {
    const int idx = (p << 8) + tid, dr = idx >> 3, ch2 = idx & 7;
    u16x8 o;
#pragma unroll
    for (int e = 0; e < 8; ++e) o[e] = T[(ch2 * 8 + e) * 68 + dr];
    *(u16x8*)(Vt + ((size_t)(bh * 64 + dr) << 10) + s0 + ch2 * 8) = o;
  }
}

// ---------------- mask fragment load (u8 or i32, nontemporal) ----------------
__device__ __forceinline__ void load_mask4(unsigned mv[4], const void* maskp, bool mi32,
                                           size_t base, int g) {
  if (mi32) {
    const int* mrow = (const int*)maskp + base + (g << 2);
#pragma unroll
    for (int mf = 0; mf < 4; ++mf) {
      const i32x4 w4 = __builtin_nontemporal_load((const i32x4*)(mrow + mf * 16));
      mv[mf] = (w4.x ? 1u : 0u) | (w4.y ? 0x100u : 0u) | (w4.z ? 0x10000u : 0u) | (w4.w ? 0x1000000u : 0u);
    }
  } else {
    const unsigned char* mrow = (const unsigned char*)maskp + base + (g << 2);
#pragma unroll
    for (int mf = 0; mf < 4; ++mf)
      mv[mf] = __builtin_nontemporal_load((const unsigned*)(mrow + mf * 16));
  }
}

// ---------------- fused flash attention ----------------
// grid 2048 (1-D), 256 thr, XCD-local bh mapping. S' = QK^T * (log2e/8) folded into
// the Q projection scale, so softmax runs natively in exp2 domain (no per-elem mul).
// S^T = K*Q^T (softmax rows lane-local, q = lane&15); O^T = V^T * P^T.
__global__ __launch_bounds__(256) void attn_kernel(
    const unsigned short* __restrict__ Qp,   // [8192][1024] bf16, pre-scaled by log2e/8
    const unsigned short* __restrict__ Kp,   // [8192][1024] bf16
    const unsigned short* __restrict__ Vt,   // [128][64][1024] bf16
    const void*           __restrict__ maskp,// [128][1024][1024] u8 or i32
    const int*            __restrict__ mflag,
    unsigned short* __restrict__ AO)         // [8192][1024] bf16
{
  const int tid = threadIdx.x;
  const int w = tid >> 6, lane = tid & 63, c = lane & 15, g = lane >> 4;
  const int bid = blockIdx.x;
  const int bh = (bid & 7) * 16 + (bid >> 7);   // XCD-local bh
  const int qb0 = ((bid >> 3) & 15) << 6;
  const int b = bh >> 4, h = bh & 15;
  const int qrow = qb0 + (w << 4) + c;
  const bool mi32 = (*mflag != 0);

  __shared__ unsigned short Ksm[2][64 * 64];    // [kk][d-chunks], XOR-swizzled
  __shared__ unsigned short Vsm[2][64 * 64];    // [d][kk-chunks], XOR-swizzled
  __shared__ unsigned short Psm[4][16 * 72];    // per-wave P[q][kk]

  bf16x8 qf[2];
  {
    const unsigned short* qp = Qp + ((size_t)(qrow * 8 + b) << 10) + (h << 6) + (g << 3);
    qf[0] = *(const bf16x8*)qp;
    qf[1] = *(const bf16x8*)(qp + 32);
  }

  const int r0s = tid >> 3, ch0 = tid & 7;
  const int wbase = (tid & ~63) * 16;           // wave-uniform LDS byte base
  const unsigned short* Vg = Vt + ((size_t)bh << 16);
  const size_t mbase0 = ((size_t)bh << 20) + ((size_t)qrow << 10);

  // stage K/V tile t_ into buffer bb_: 4 async16 per thread (K0,V0,K1,V1)
#define ASTAGE(t_, bb_) do { const int kk_ = (t_) << 6;                           \
    _Pragma("unroll") for (int i_ = 0; i_ < 2; ++i_) {                            \
      const int row_ = i_ * 32 + r0s;                                             \
      const int kc_ = ch0 ^ (row_ & 7);                                           \
      async16(Kp + ((size_t)((kk_ + row_) * 8 + b) << 10) + (h << 6) + (kc_ << 3),\
              (char*)&Ksm[bb_][0] + (i_ << 12) + wbase);                          \
      async16(Vg + ((size_t)row_ << 10) + kk_ + (kc_ << 3),                       \
              (char*)&Vsm[bb_][0] + (i_ << 12) + wbase);                          \
    } } while (0)

  // LDS[row][chunk j] holds global chunk j^(row&7)
#define ARD(arr_, bb_, row_, ks_) \
    (*(const bf16x8*)&arr_[bb_][(row_) * 64 + ((((ks_) * 4 + g) ^ ((row_) & 7)) << 3)])

  ASTAGE(0, 0);
  ASTAGE(1, 1);
  unsigned mv[4], mvN[4];
  load_mask4(mv,  maskp, mi32, mbase0,      g);
  load_mask4(mvN, maskp, mi32, mbase0 + 64, g);

  f32x4 oacc[4];
#pragma unroll
  for (int i = 0; i < 4; ++i) oacc[i] = (f32x4){0.f, 0.f, 0.f, 0.f};
  float mrun = -1e30f, lrun = 0.f;

  for (int t = 0; t < 16; ++t) {
    if (t == 15) asm volatile("s_waitcnt vmcnt(0)" ::: "memory");
    else         asm volatile("s_waitcnt vmcnt(4)" ::: "memory");
    __builtin_amdgcn_sched_barrier(0);
    __builtin_amdgcn_s_barrier();               // tile t landed for all waves
    __builtin_amdgcn_sched_barrier(0);
    const int buf = t & 1;

    unsigned mvN2[4];
    if (t < 14)                                  // mask 2 tiles ahead
      load_mask4(mvN2, maskp, mi32, mbase0 + (t << 6) + 128, g);

    // S^T tile: rows kk = mf*16+g*4+j, col q = c  (exp2 domain)
    f32x4 sacc[4];
#pragma unroll
    for (int i = 0; i < 4; ++i) sacc[i] = (f32x4){0.f, 0.f, 0.f, 0.f};
#pragma unroll
    for (int d2 = 0; d2 < 2; ++d2) {
#pragma unroll
      for (int mf = 0; mf < 4; ++mf) {
        bf16x8 kf = ARD(Ksm, buf, mf * 16 + c, d2);
        sacc[mf] = __builtin_amdgcn_mfma_f32_16x16x32_bf16(kf, qf[d2], sacc[mf], 0, 0, 0);
      }
    }
    // mask + online softmax (exp2 domain: no LOG2E muls)
    float tmax = -1e30f;
#pragma unroll
    for (int mf = 0; mf < 4; ++mf)
#pragma unroll
      for (int j = 0; j < 4; ++j) {
        float s = sacc[mf][j];
        if ((mv[mf] >> (8 * j)) & 0xffu) s = -1e30f;
        sacc[mf][j] = s;
        tmax = fmaxf(tmax, s);
      }
    tmax = fmaxf(tmax, __shfl_xor(tmax, 16));
    tmax = fmaxf(tmax, __shfl_xor(tmax, 32));
    const float mnew = fmaxf(mrun, tmax);
    const float alpha = __builtin_amdgcn_exp2f(mrun - mnew);
    float tsum = 0.f;
    float pv[4][4];
#pragma unroll
    for (int mf = 0; mf < 4; ++mf)
#pragma unroll
      for (int j = 0; j < 4; ++j) {
        const float p = __builtin_amdgcn_exp2f(sacc[mf][j] - mnew);
        pv[mf][j] = p;
        tsum += p;
      }
    tsum += __shfl_xor(tsum, 16);
    tsum += __shfl_xor(tsum, 32);
    lrun = lrun * alpha + tsum;
    mrun = mnew;
#pragma unroll
    for (int i = 0; i < 4; ++i) {
      oacc[i][0] *= alpha; oacc[i][1] *= alpha; oacc[i][2] *= alpha; oacc[i][3] *= alpha;
    }
#pragma unroll
    for (int mf = 0; mf < 4; ++mf) {
      uint2 t2;
      t2.x = pk2(pv[mf][0], pv[mf][1]);
      t2.y = pk2(pv[mf][2], pv[mf][3]);
      *(uint2*)&Psm[w][c * 72 + mf * 16 + (g << 2)] = t2;
    }
#pragma unroll
    for (int ks = 0; ks < 2; ++ks) {
      bf16x8 pf = *(const bf16x8*)&Psm[w][c * 72 + ks * 32 + (g << 3)];
#pragma unroll
      for (int mf = 0; mf < 4; ++mf) {
        bf16x8 vf = ARD(Vsm, buf, mf * 16 + c, ks);
        oacc[mf] = __builtin_amdgcn_mfma_f32_16x16x32_bf16(vf, pf, oacc[mf], 0, 0, 0);
      }
    }
    __builtin_amdgcn_sched_barrier(0);
    __builtin_amdgcn_s_barrier();               // all waves done reading buf
    __builtin_amdgcn_sched_barrier(0);
    if (t < 14) ASTAGE(t + 2, buf);             // overwrite just-read buf
#pragma unroll
    for (int i = 0; i < 4; ++i) { mv[i] = mvN[i]; mvN[i] = mvN2[i]; }
  }
#undef ASTAGE
#undef ARD
  const float inv = 1.0f / lrun;
#pragma unroll
  for (int mf = 0; mf < 4; ++mf) {
    uint2 t2;
    t2.x = pk2(oacc[mf][0] * inv, oacc[mf][1] * inv);
    t2.y = pk2(oacc[mf][2] * inv, oacc[mf][3] * inv);
    *(uint2*)(AO + ((size_t)(qrow * 8 + b) << 10) + (h << 6) + mf * 16 + (g << 2)) = t2;
  }
}

// ---------------- host ----------------
extern "C" void kernel_launch(void* const* d_in, const int* in_sizes, int n_in,
                              void* d_out, int out_size, void* d_ws, size_t ws_size,
                              hipStream_t stream)
{
  const float* q  = (const float*)d_in[0];
  const float* k  = (const float*)d_in[1];
  const float* v  = (const float*)d_in[2];
  const void*  mask = (const void*)d_in[3];
  const float* wq = (const float*)d_in[4];
  const float* wk = (const float*)d_in[5];
  const float* wv = (const float*)d_in[6];
  const float* wo = (const float*)d_in[7];

  unsigned short* ws  = (unsigned short*)d_ws;   // ~104 MiB used
  unsigned short* Xin = ws;                      // 3 x 8388608 (bf16 q,k,v)
  unsigned short* Wbf = ws + 25165824u;          // 4 x 1048576
  unsigned short* Xp  = ws + 29360128u;          // 3 x 8388608 (projected)
  int* mfl            = (int*)(ws + 54525952u);
  unsigned short* Vt  = ws + 8388608u;           // aliases Xin[1] (dead after K projection)
  unsigned short* AO  = ws;                      // aliases Xin[0] (dead after Q projection)

  const float QSCALE = 0.125f * LOG2E;           // exp2-domain softmax

  detect_mask<<<1, 64, 0, stream>>>((const unsigned*)mask, mfl);
  cvt_kernel<<<14336, 256, 0, stream>>>(q, k, v, wq, wk, wv, wo, Xin, Wbf);
  gemm128<0><<<1536, 256, 0, stream>>>(Xin, Wbf, Xp, QSCALE, 8192, 1024, 1024);   // Q,K,V merged
  transpose_v<<<dim3(16, 128), 256, 0, stream>>>(Xp + 16777216u, Vt);
  attn_kernel<<<2048, 256, 0, stream>>>(Xp, Xp + 8388608u, Vt, mask, mfl, AO);
  gemm128<1><<<512, 256, 0, stream>>>(AO, Wbf + 3145728u, d_out, 1.0f, 8192, 1024, 1024);
}

// Round 15
// 289.518 us; speedup vs baseline: 1.0279x; 1.0279x over previous
//
#include <hip/hip_runtime.h>

// MultiHeadAttention3D: S=1024, B=8, E=1024, H=16, D=64.
// Pipeline: detect mask dtype -> cvt(f32->bf16) -> merged QKV proj GEMM (128x128,
//           BK=64, counted-vmcnt dbuf, 2 blocks/CU) -> V transpose -> fused flash
//           attention (swapped-QK, exp2-domain softmax, setprio) -> Wo GEMM (f32 out).

typedef __attribute__((ext_vector_type(8))) short bf16x8;       // MFMA A/B frag (8 bf16)
typedef __attribute__((ext_vector_type(8))) unsigned short u16x8;
typedef __attribute__((ext_vector_type(4))) float f32x4;
typedef __attribute__((ext_vector_type(4))) int i32x4;

#define LOG2E 1.44269504088896340736f

__device__ __forceinline__ unsigned short bfbits(float f) {    // f32 -> bf16 (RTNE)
  unsigned u = __builtin_bit_cast(unsigned, f);
  u += 0x7fffu + ((u >> 16) & 1u);
  return (unsigned short)(u >> 16);
}
__device__ __forceinline__ unsigned pk2(float a, float b) {
  return (unsigned)bfbits(a) | ((unsigned)bfbits(b) << 16);
}
__device__ __forceinline__ void async16(const void* src, void* dst_lds) {
  __builtin_amdgcn_global_load_lds(
      (const __attribute__((address_space(1))) unsigned int*)src,
      (__attribute__((address_space(3))) unsigned int*)dst_lds, 16, 0, 0);
}

// ---------------- mask dtype detection ----------------
__global__ void detect_mask(const unsigned* __restrict__ m, int* __restrict__ flag)
{
  unsigned ok = 1u;
#pragma unroll 8
  for (int i = 0; i < 64; ++i) {
    unsigned w = m[(threadIdx.x << 6) + i];
    ok &= (w <= 1u) ? 1u : 0u;
  }
  unsigned long long vote = __ballot(ok != 0u);
  if (threadIdx.x == 0) *flag = (vote == ~0ull) ? 1 : 0;
}

// ---------------- convert q,k,v,W* to bf16 ----------------
__global__ __launch_bounds__(256) void cvt_kernel(
    const float* __restrict__ q, const float* __restrict__ k, const float* __restrict__ v,
    const float* __restrict__ wq, const float* __restrict__ wk,
    const float* __restrict__ wv, const float* __restrict__ wo,
    unsigned short* __restrict__ Xin, unsigned short* __restrict__ Wbf)
{
  const unsigned u = blockIdx.x * 256u + threadIdx.x;   // 3670016 units of 8 elems
  const float* src;
  unsigned short* dst;
  if (u < 3145728u) {                      // q,k,v
    const unsigned z = u >> 20, r = u & 1048575u;
    src = (z == 0 ? q : z == 1 ? k : v) + (size_t)r * 8;
    dst = Xin + (size_t)z * 8388608u + (size_t)r * 8;
  } else {                                 // Wq,Wk,Wv,Wo
    const unsigned u2 = u - 3145728u, wz = u2 >> 17, r = u2 & 131071u;
    src = (wz == 0 ? wq : wz == 1 ? wk : wz == 2 ? wv : wo) + (size_t)r * 8;
    dst = Wbf + (size_t)wz * 1048576u + (size_t)r * 8;
  }
  f32x4 a = *(const f32x4*)src;
  f32x4 b = *(const f32x4*)(src + 4);
  uint4 o;
  o.x = pk2(a[0], a[1]); o.y = pk2(a[2], a[3]);
  o.z = pk2(b[0], b[1]); o.w = pk2(b[2], b[3]);
  *(uint4*)dst = o;
}

// ---------------- GEMM: 128x128 tile, BK=64, counted-vmcnt dbuf, 2 blocks/CU ----------------
template<int OUTF32>
__global__ __launch_bounds__(256) void gemm128(
    const unsigned short* __restrict__ A0,  // [M][K] bf16 (+ p*8388608)
    const unsigned short* __restrict__ B0,  // [N][K] bf16 (+ p*1048576)
    void* __restrict__ C0, float scale0, int M, int N, int K)
{
  const int tid = threadIdx.x;
  const int w = tid >> 6, lane = tid & 63, c = lane & 15, g = lane >> 4;
  const int wr = w >> 1, wc = w & 1;

  const int bid = blockIdx.x;
  const int p = bid >> 9, local = bid & 511;
  const unsigned short* A = A0 + (size_t)p * 8388608u;
  const unsigned short* B = B0 + (size_t)p * 1048576u;
  const float scale = (p == 0) ? scale0 : 1.0f;

  // XCD-chunked swizzle within the 512-block sub-grid
  const int swz = (local & 7) * 64 + (local >> 3);
  const int ntx = N >> 7;
  const int bx = swz % ntx, by = swz / ntx;
  const int rowA = by * 128, rowB = bx * 128;

  __shared__ unsigned short As[2][128 * 64];   // 2 x 16 KiB
  __shared__ unsigned short Bs[2][128 * 64];   // 2 x 16 KiB

  f32x4 acc[4][4];
#pragma unroll
  for (int i = 0; i < 4; ++i)
#pragma unroll
    for (int j = 0; j < 4; ++j) acc[i][j] = (f32x4){0.f, 0.f, 0.f, 0.f};

  const int wbase = (tid & ~63) * 16;          // wave-uniform LDS byte base (linear dest)

#define STAGE(kt_, bb_) do { const int k0_ = (kt_) << 6;                          \
    _Pragma("unroll") for (int i_ = 0; i_ < 4; ++i_) {                            \
      const int slot_ = i_ * 256 + tid;                                           \
      const int row_ = slot_ >> 3;                                                \
      const int kc_ = (slot_ & 7) ^ (row_ & 7);                                   \
      async16(A + (size_t)(rowA + row_) * K + k0_ + kc_ * 8,                      \
              (char*)&As[bb_][0] + (i_ << 12) + wbase);                           \
      async16(B + (size_t)(rowB + row_) * K + k0_ + kc_ * 8,                      \
              (char*)&Bs[bb_][0] + (i_ << 12) + wbase);                           \
    } } while (0)

  // LDS[row][j] holds global chunk j^(row&7); to read chunk (ks*4+g): j = (ks*4+g)^(row&7)
#define RD(arr_, bb_, row_, ks_) \
    (*(const bf16x8*)&arr_[bb_][(row_) * 64 + ((((ks_) * 4 + g) ^ ((row_) & 7)) << 3)])

#define COMPUTE(bb_) do {                                                         \
    bf16x8 af_[4][2], bf_[4][2];                                                  \
    _Pragma("unroll") for (int x_ = 0; x_ < 4; ++x_)                              \
      _Pragma("unroll") for (int ks_ = 0; ks_ < 2; ++ks_) {                       \
        af_[x_][ks_] = RD(As, bb_, wr * 64 + x_ * 16 + c, ks_);                   \
        bf_[x_][ks_] = RD(Bs, bb_, wc * 64 + x_ * 16 + c, ks_);                   \
      }                                                                           \
    _Pragma("unroll") for (int ks_ = 0; ks_ < 2; ++ks_)                           \
      _Pragma("unroll") for (int mf_ = 0; mf_ < 4; ++mf_)                         \
        _Pragma("unroll") for (int nf_ = 0; nf_ < 4; ++nf_)                       \
          acc[mf_][nf_] = __builtin_amdgcn_mfma_f32_16x16x32_bf16(                \
              af_[mf_][ks_], bf_[nf_][ks_], acc[mf_][nf_], 0, 0, 0); } while (0)

  STAGE(0, 0);
  STAGE(1, 1);

  for (int kt = 0; kt < 15; ++kt) {
    asm volatile("s_waitcnt vmcnt(8)" ::: "memory");   // tile kt landed; kt+1 in flight
    __builtin_amdgcn_sched_barrier(0);
    __builtin_amdgcn_s_barrier();
    __builtin_amdgcn_sched_barrier(0);
    const int buf = kt & 1;
    COMPUTE(buf);
    __builtin_amdgcn_sched_barrier(0);
    __builtin_amdgcn_s_barrier();                      // all waves done reading buf
    __builtin_amdgcn_sched_barrier(0);
    if (kt < 14) STAGE(kt + 2, buf);                   // overwrite just-computed buf
  }
  asm volatile("s_waitcnt vmcnt(0)" ::: "memory");     // tile 15 landed
  __builtin_amdgcn_sched_barrier(0);
  __builtin_amdgcn_s_barrier();
  __builtin_amdgcn_sched_barrier(0);
  COMPUTE(1);

#undef STAGE
#undef RD
#undef COMPUTE

  const int r0 = rowA + wr * 64, c0 = rowB + wc * 64;
  if (OUTF32) {
    float* O = (float*)C0;
#pragma unroll
    for (int mf = 0; mf < 4; ++mf)
#pragma unroll
      for (int nf = 0; nf < 4; ++nf)
#pragma unroll
        for (int j = 0; j < 4; ++j)
          O[(size_t)(r0 + mf * 16 + g * 4 + j) * N + c0 + nf * 16 + c] = acc[mf][nf][j] * scale;
  } else {
    unsigned short* O = (unsigned short*)C0 + (size_t)p * 8388608u;
#pragma unroll
    for (int mf = 0; mf < 4; ++mf)
#pragma unroll
      for (int nf = 0; nf < 4; ++nf)
#pragma unroll
        for (int j = 0; j < 4; ++j)
          O[(size_t)(r0 + mf * 16 + g * 4 + j) * N + c0 + nf * 16 + c] = bfbits(acc[mf][nf][j] * scale);
  }
}

// ---------------- Vt[bh][d][s] = Vproj[(s*8+b)][h*64+d] ----------------
__global__ __launch_bounds__(256) void transpose_v(
    const unsigned short* __restrict__ Xp2, unsigned short* __restrict__ Vt)
{
  const int tid = threadIdx.x;
  const int bh = blockIdx.y, b = bh >> 4, h = bh & 15;
  const int s0 = blockIdx.x << 6;
  __shared__ unsigned short T[64 * 68];
#pragma unroll
  for (int p = 0; p < 2; ++p) {
    const int idx = (p << 8) + tid, sr = idx >> 3, ch2 = idx & 7;
    *(u16x8*)&T[sr * 68 + ch2 * 8] =
        *(const u16x8*)(Xp2 + ((size_t)((s0 + sr) * 8 + b) << 10) + (h << 6) + ch2 * 8);
  }
  __syncthreads();
#pragma unroll
  for (int p = 0; p < 2; ++p) {
    const int idx = (p << 8) + tid, dr = idx >> 3, ch2 = idx & 7;
    u16x8 o;
#pragma unroll
    for (int e = 0; e < 8; ++e) o[e] = T[(ch2 * 8 + e) * 68 + dr];
    *(u16x8*)(Vt + ((size_t)(bh * 64 + dr) << 10) + s0 + ch2 * 8) = o;
  }
}

// ---------------- mask fragment load (u8 or i32, nontemporal) ----------------
__device__ __forceinline__ void load_mask4(unsigned mv[4], const void* maskp, bool mi32,
                                           size_t base, int g) {
  if (mi32) {
    const int* mrow = (const int*)maskp + base + (g << 2);
#pragma unroll
    for (int mf = 0; mf < 4; ++mf) {
      const i32x4 w4 = __builtin_nontemporal_load((const i32x4*)(mrow + mf * 16));
      mv[mf] = (w4.x ? 1u : 0u) | (w4.y ? 0x100u : 0u) | (w4.z ? 0x10000u : 0u) | (w4.w ? 0x1000000u : 0u);
    }
  } else {
    const unsigned char* mrow = (const unsigned char*)maskp + base + (g << 2);
#pragma unroll
    for (int mf = 0; mf < 4; ++mf)
      mv[mf] = __builtin_nontemporal_load((const unsigned*)(mrow + mf * 16));
  }
}

// ---------------- fused flash attention ----------------
// grid 2048 (1-D), 256 thr, XCD-local bh mapping. Q pre-scaled by log2e/8 so
// softmax runs natively in exp2 domain. S^T = K*Q^T; O^T = V^T * P^T.
// K/V staged via global_load_lds, dbuf XOR-swizzled LDS, counted vmcnt(4).
__global__ __launch_bounds__(256) void attn_kernel(
    const unsigned short* __restrict__ Qp,   // [8192][1024] bf16, pre-scaled by log2e/8
    const unsigned short* __restrict__ Kp,   // [8192][1024] bf16
    const unsigned short* __restrict__ Vt,   // [128][64][1024] bf16
    const void*           __restrict__ maskp,// [128][1024][1024] u8 or i32
    const int*            __restrict__ mflag,
    unsigned short* __restrict__ AO)         // [8192][1024] bf16
{
  const int tid = threadIdx.x;
  const int w = tid >> 6, lane = tid & 63, c = lane & 15, g = lane >> 4;
  const int bid = blockIdx.x;
  const int bh = (bid & 7) * 16 + (bid >> 7);   // XCD-local bh
  const int qb0 = ((bid >> 3) & 15) << 6;
  const int b = bh >> 4, h = bh & 15;
  const int qrow = qb0 + (w << 4) + c;
  const bool mi32 = (*mflag != 0);

  __shared__ unsigned short Ksm[2][64 * 64];    // [kk][d-chunks], XOR-swizzled
  __shared__ unsigned short Vsm[2][64 * 64];    // [d][kk-chunks], XOR-swizzled
  __shared__ unsigned short Psm[4][16 * 72];    // per-wave P[q][kk]

  bf16x8 qf[2];
  {
    const unsigned short* qp = Qp + ((size_t)(qrow * 8 + b) << 10) + (h << 6) + (g << 3);
    qf[0] = *(const bf16x8*)qp;
    qf[1] = *(const bf16x8*)(qp + 32);
  }

  const int r0s = tid >> 3, ch0 = tid & 7;
  const int wbase = (tid & ~63) * 16;           // wave-uniform LDS byte base
  const unsigned short* Vg = Vt + ((size_t)bh << 16);
  const size_t mbase0 = ((size_t)bh << 20) + ((size_t)qrow << 10);

  // stage K/V tile t_ into buffer bb_: 4 async16 per thread (K0,V0,K1,V1)
#define ASTAGE(t_, bb_) do { const int kk_ = (t_) << 6;                           \
    _Pragma("unroll") for (int i_ = 0; i_ < 2; ++i_) {                            \
      const int row_ = i_ * 32 + r0s;                                             \
      const int kc_ = ch0 ^ (row_ & 7);                                           \
      async16(Kp + ((size_t)((kk_ + row_) * 8 + b) << 10) + (h << 6) + (kc_ << 3),\
              (char*)&Ksm[bb_][0] + (i_ << 12) + wbase);                          \
      async16(Vg + ((size_t)row_ << 10) + kk_ + (kc_ << 3),                       \
              (char*)&Vsm[bb_][0] + (i_ << 12) + wbase);                          \
    } } while (0)

  // LDS[row][chunk j] holds global chunk j^(row&7)
#define ARD(arr_, bb_, row_, ks_) \
    (*(const bf16x8*)&arr_[bb_][(row_) * 64 + ((((ks_) * 4 + g) ^ ((row_) & 7)) << 3)])

  ASTAGE(0, 0);
  ASTAGE(1, 1);
  unsigned mv[4], mvN[4];
  load_mask4(mv,  maskp, mi32, mbase0,      g);
  load_mask4(mvN, maskp, mi32, mbase0 + 64, g);

  f32x4 oacc[4];
#pragma unroll
  for (int i = 0; i < 4; ++i) oacc[i] = (f32x4){0.f, 0.f, 0.f, 0.f};
  float mrun = -1e30f, lrun = 0.f;

  for (int t = 0; t < 16; ++t) {
    if (t == 15) asm volatile("s_waitcnt vmcnt(0)" ::: "memory");
    else         asm volatile("s_waitcnt vmcnt(4)" ::: "memory");
    __builtin_amdgcn_sched_barrier(0);
    __builtin_amdgcn_s_barrier();               // tile t landed for all waves
    __builtin_amdgcn_sched_barrier(0);
    const int buf = t & 1;

    unsigned mvN2[4];
    if (t < 14)                                  // mask 2 tiles ahead
      load_mask4(mvN2, maskp, mi32, mbase0 + (t << 6) + 128, g);

    // S^T tile: rows kk = mf*16+g*4+j, col q = c  (exp2 domain)
    f32x4 sacc[4];
#pragma unroll
    for (int i = 0; i < 4; ++i) sacc[i] = (f32x4){0.f, 0.f, 0.f, 0.f};
    __builtin_amdgcn_s_setprio(1);
#pragma unroll
    for (int d2 = 0; d2 < 2; ++d2) {
#pragma unroll
      for (int mf = 0; mf < 4; ++mf) {
        bf16x8 kf = ARD(Ksm, buf, mf * 16 + c, d2);
        sacc[mf] = __builtin_amdgcn_mfma_f32_16x16x32_bf16(kf, qf[d2], sacc[mf], 0, 0, 0);
      }
    }
    __builtin_amdgcn_s_setprio(0);
    // mask + online softmax (exp2 domain: no LOG2E muls)
    float tmax = -1e30f;
#pragma unroll
    for (int mf = 0; mf < 4; ++mf)
#pragma unroll
      for (int j = 0; j < 4; ++j) {
        float s = sacc[mf][j];
        if ((mv[mf] >> (8 * j)) & 0xffu) s = -1e30f;
        sacc[mf][j] = s;
        tmax = fmaxf(tmax, s);
      }
    tmax = fmaxf(tmax, __shfl_xor(tmax, 16));
    tmax = fmaxf(tmax, __shfl_xor(tmax, 32));
    const float mnew = fmaxf(mrun, tmax);
    const float alpha = __builtin_amdgcn_exp2f(mrun - mnew);
    float tsum = 0.f;
    float pv[4][4];
#pragma unroll
    for (int mf = 0; mf < 4; ++mf)
#pragma unroll
      for (int j = 0; j < 4; ++j) {
        const float p = __builtin_amdgcn_exp2f(sacc[mf][j] - mnew);
        pv[mf][j] = p;
        tsum += p;
      }
    tsum += __shfl_xor(tsum, 16);
    tsum += __shfl_xor(tsum, 32);
    lrun = lrun * alpha + tsum;
    mrun = mnew;
#pragma unroll
    for (int i = 0; i < 4; ++i) {
      oacc[i][0] *= alpha; oacc[i][1] *= alpha; oacc[i][2] *= alpha; oacc[i][3] *= alpha;
    }
#pragma unroll
    for (int mf = 0; mf < 4; ++mf) {
      uint2 t2;
      t2.x = pk2(pv[mf][0], pv[mf][1]);
      t2.y = pk2(pv[mf][2], pv[mf][3]);
      *(uint2*)&Psm[w][c * 72 + mf * 16 + (g << 2)] = t2;
    }
    __builtin_amdgcn_s_setprio(1);
#pragma unroll
    for (int ks = 0; ks < 2; ++ks) {
      bf16x8 pf = *(const bf16x8*)&Psm[w][c * 72 + ks * 32 + (g << 3)];
#pragma unroll
      for (int mf = 0; mf < 4; ++mf) {
        bf16x8 vf = ARD(Vsm, buf, mf * 16 + c, ks);
        oacc[mf] = __builtin_amdgcn_mfma_f32_16x16x32_bf16(vf, pf, oacc[mf], 0, 0, 0);
      }
    }
    __builtin_amdgcn_s_setprio(0);
    __builtin_amdgcn_sched_barrier(0);
    __builtin_amdgcn_s_barrier();               // all waves done reading buf
    __builtin_amdgcn_sched_barrier(0);
    if (t < 14) ASTAGE(t + 2, buf);             // overwrite just-read buf
#pragma unroll
    for (int i = 0; i < 4; ++i) { mv[i] = mvN[i]; mvN[i] = mvN2[i]; }
  }
#undef ASTAGE
#undef ARD
  const float inv = 1.0f / lrun;
#pragma unroll
  for (int mf = 0; mf < 4; ++mf) {
    uint2 t2;
    t2.x = pk2(oacc[mf][0] * inv, oacc[mf][1] * inv);
    t2.y = pk2(oacc[mf][2] * inv, oacc[mf][3] * inv);
    *(uint2*)(AO + ((size_t)(qrow * 8 + b) << 10) + (h << 6) + mf * 16 + (g << 2)) = t2;
  }
}

// ---------------- host ----------------
extern "C" void kernel_launch(void* const* d_in, const int* in_sizes, int n_in,
                              void* d_out, int out_size, void* d_ws, size_t ws_size,
                              hipStream_t stream)
{
  const float* q  = (const float*)d_in[0];
  const float* k  = (const float*)d_in[1];
  const float* v  = (const float*)d_in[2];
  const void*  mask = (const void*)d_in[3];
  const float* wq = (const float*)d_in[4];
  const float* wk = (const float*)d_in[5];
  const float* wv = (const float*)d_in[6];
  const float* wo = (const float*)d_in[7];

  unsigned short* ws  = (unsigned short*)d_ws;   // ~104 MiB used
  unsigned short* Xin = ws;                      // 3 x 8388608 (bf16 q,k,v)
  unsigned short* Wbf = ws + 25165824u;          // 4 x 1048576
  unsigned short* Xp  = ws + 29360128u;          // 3 x 8388608 (projected)
  int* mfl            = (int*)(ws + 54525952u);
  unsigned short* Vt  = ws + 8388608u;           // aliases Xin[1] (dead after K projection)
  unsigned short* AO  = ws;                      // aliases Xin[0] (dead after Q projection)

  const float QSCALE = 0.125f * LOG2E;           // exp2-domain softmax

  detect_mask<<<1, 64, 0, stream>>>((const unsigned*)mask, mfl);
  cvt_kernel<<<14336, 256, 0, stream>>>(q, k, v, wq, wk, wv, wo, Xin, Wbf);
  gemm128<0><<<1536, 256, 0, stream>>>(Xin, Wbf, Xp, QSCALE, 8192, 1024, 1024);   // Q,K,V merged
  transpose_v<<<dim3(16, 128), 256, 0, stream>>>(Xp + 16777216u, Vt);
  attn_kernel<<<2048, 256, 0, stream>>>(Xp, Xp + 8388608u, Vt, mask, mfl, AO);
  gemm128<1><<<512, 256, 0, stream>>>(AO, Wbf + 3145728u, d_out, 1.0f, 8192, 1024, 1024);
}